// Round 13
// baseline (300.621 us; speedup 1.0000x reference)
//
#include <hip/hip_runtime.h>
#include <stdint.h>

#define DIM 1024
#define NH 16
#define DH 64
#define BATCH 4
#define SEQ 2048
#define MROWS (BATCH*SEQ)  // 8192

typedef _Float16 half8 __attribute__((ext_vector_type(8)));
typedef __fp16 fp16x2 __attribute__((ext_vector_type(2)));
typedef float f32x4 __attribute__((ext_vector_type(4)));
typedef float f32x16 __attribute__((ext_vector_type(16)));
typedef unsigned int u32x2 __attribute__((ext_vector_type(2)));

__device__ __forceinline__ unsigned short f2h(float f) {
    union { _Float16 h; unsigned short u; } c; c.h = (_Float16)f; return c.u;
}
__device__ __forceinline__ unsigned int pk2u(float a, float b) {
    union { fp16x2 h; unsigned int u; } c;
    c.h = __builtin_amdgcn_cvt_pkrtz(a, b);
    return c.u;
}
// raw v_exp_f32 (1 inst; exp2f without -ffast-math goes through ocml libm)
__device__ __forceinline__ float fexp2(float x) {
    return __builtin_amdgcn_exp2f(x);
}
// async 16B/lane global->LDS (lds dest = wave-uniform base + lane*16)
__device__ __forceinline__ void gl_lds16(const unsigned short* g, unsigned short* l) {
    __builtin_amdgcn_global_load_lds(
        (__attribute__((address_space(1))) void*)(void*)g,
        (__attribute__((address_space(3))) void*)(void*)l,
        16, 0, 0);
}
// counted-vmcnt barrier pair helpers (T4): never drain vmcnt to 0 mid-loop.
#define SFENCE __builtin_amdgcn_sched_barrier(0)
#define SBAR   __builtin_amdgcn_s_barrier()
#define VMCNT4 asm volatile("s_waitcnt vmcnt(4)" ::: "memory")
#define VMCNT0 asm volatile("s_waitcnt vmcnt(0)" ::: "memory")

// ---------------- merged cast + weight prep (one launch) ----------------
// 1D grid 9216: blocks 0..8191 cast x (fp32->f16, 1024 float4/block exact);
// blocks 8192..9215 decode (d0, y, mat): mat 0..2 -> wt transpose, 3 -> wot.
__global__ __launch_bounds__(256) void cast_prep_kernel(
    const float* __restrict__ x, unsigned short* __restrict__ xh,
    const float* __restrict__ Wq, const float* __restrict__ Wk,
    const float* __restrict__ Wv, const float* __restrict__ Wo,
    unsigned short* __restrict__ wt, unsigned short* __restrict__ wot)
{
    __shared__ unsigned short tile[64][65];
    const int bid = blockIdx.x;
    if (bid < 8192) {
        const int i = bid * 256 + threadIdx.x;   // n4 = 8192*256 exactly
        float4 v = reinterpret_cast<const float4*>(x)[i];
        uint2 o;
        o.x = pk2u(v.x, v.y);
        o.y = pk2u(v.z, v.w);
        reinterpret_cast<uint2*>(xh)[i] = o;
        return;
    }
    const int local = bid - 8192;
    const int d0 = (local & 15) * 64;
    const int y = (local >> 4) & 15;
    const int mat = local >> 8;
    const int c = threadIdx.x & 63;
    const int rr = threadIdx.x >> 6;

    if (mat < 3) {
        const float* W = (mat == 0) ? Wq : ((mat == 1) ? Wk : Wv);
#pragma unroll
        for (int p = 0; p < 16; p++) {
            int dl = p * 4 + rr;
            tile[dl][c] = f2h(W[((size_t)y * 1024 + d0 + dl) * 64 + c]);
        }
        __syncthreads();
#pragma unroll
        for (int p = 0; p < 16; p++) {
            int el = p * 4 + rr;
            wt[(((size_t)(mat * NH + y) * 64) + el) * DIM + d0 + c] = tile[c][el];
        }
    } else {
        const int o0 = y * 64;
#pragma unroll
        for (int p = 0; p < 16; p++) {
            int dl = p * 4 + rr;
            tile[dl][c] = f2h(Wo[(size_t)(d0 + dl) * DIM + o0 + c]);
        }
        __syncthreads();
#pragma unroll
        for (int p = 0; p < 16; p++) {
            int ol = p * 4 + rr;
            wot[(size_t)(o0 + ol) * DIM + d0 + c] = tile[c][ol];
        }
    }
}

// ---------------- QKV projection GEMM (32x32x16 MFMA, 128x128, BK=32) ----
// 1D grid 1536, XCD-swizzled (bijective: 1536 = 8*192). 8 MFMA/K-step.
// This rev: counted-vmcnt barrier scheme (T4). Each iter: SBAR (WAR: all
// reads of the overwrite target done) -> issue stage(i+1) (4 loads/wave) ->
// vmcnt(4) (retires exactly stage(i)'s loads) -> SBAR (RAW) -> compute(i).
// Staged loads get a full compute-phase in flight instead of being drained
// by __syncthreads' vmcnt(0) in the same iteration.
__global__ __launch_bounds__(256) void qkv_gemm_kernel(
    const unsigned short* __restrict__ xh,   // [8192][1024] f16
    const unsigned short* __restrict__ wt,   // [3][16][64][1024] f16
    const float* __restrict__ bq, const float* __restrict__ bk,
    const float* __restrict__ bv,
    unsigned short* __restrict__ Qb,         // [B][H][S][DH] (scaled)
    unsigned short* __restrict__ Kb,         // [B][H][S][DH]
    unsigned short* __restrict__ Vt)         // [B][H][DH][S]
{
    // ---- XCD-aware decomposition (bijective: 1536 = 8 * 192) ----
    const int bid = blockIdx.x;
    const int xcd = bid & 7;
    const int local = bid >> 3;              // 0..191
    const int rowblk = xcd * 8 + local / 24; // 0..63
    const int rem = local % 24;
    const int hpair = rem & 7;
    const int mat = rem >> 3;                // 0..2

    const int wave = threadIdx.x >> 6;
    const int lane = threadIdx.x & 63;
    const int ql = lane & 31;
    const int hi = lane >> 5;
    const int mhalf = wave & 1;
    const int nhalf = wave >> 1;

    // pool: staging Ab[2]/Bt[2] (32KB) OR V-transpose tile [128 e][128 s] swz
    __shared__ __align__(16) unsigned short pool[16384];
    unsigned short* AbP = pool;              // [2][128*32]
    unsigned short* BtP = pool + 8192;       // [2][128*32]

    const unsigned short* Asrc = xh + (size_t)rowblk * 128 * DIM;
    const unsigned short* Bsrc = wt + (size_t)(mat * NH + hpair * 2) * DH * DIM;

    const int srow = lane >> 2;    // 0..15 row within 16-row group
    const int scs = lane & 3;      // chunk slot 0..3 (8 f16 each)

    f32x16 z16;
#pragma unroll
    for (int e = 0; e < 16; e++) z16[e] = 0.f;
    f32x16 acc[2][2];
#pragma unroll
    for (int mt = 0; mt < 2; mt++)
#pragma unroll
        for (int nt = 0; nt < 2; nt++) acc[mt][nt] = z16;

    // staging: chunk c of row r lands at slot c ^ ((r>>1)&3) ^ ((r>>3)&3)
    auto stage = [&](int k0, int sel) {
#pragma unroll
        for (int jj = 0; jj < 2; jj++) {
            const int j = wave * 2 + jj;            // 0..7 (16 rows each)
            const int r = j * 16 + srow;            // 0..127
            const int cg = scs ^ ((srow >> 1) & 3) ^ ((j * 2 + (srow >> 3)) & 3);
            gl_lds16(Asrc + (size_t)r * DIM + k0 + cg * 8, AbP + sel * 4096 + j * 512);
            gl_lds16(Bsrc + (size_t)r * DIM + k0 + cg * 8, BtP + sel * 4096 + j * 512);
        }
    };

    // read offsets (loop-invariant): row = base + ql -> swz depends on ql only
    const int slotx = ((ql >> 1) & 3) ^ ((ql >> 3) & 3);
    int arow[2], brow[2], sks[2];
#pragma unroll
    for (int t = 0; t < 2; t++) {
        arow[t] = (mhalf * 64 + t * 32 + ql) * 32;
        brow[t] = (nhalf * 64 + t * 32 + ql) * 32;
    }
#pragma unroll
    for (int ks = 0; ks < 2; ks++) sks[ks] = ((ks * 2 + hi) ^ slotx) * 8;

    auto compute = [&](int sel) {
#pragma unroll
        for (int ks = 0; ks < 2; ks++) {
            half8 a0 = *reinterpret_cast<const half8*>(AbP + sel * 4096 + arow[0] + sks[ks]);
            half8 a1 = *reinterpret_cast<const half8*>(AbP + sel * 4096 + arow[1] + sks[ks]);
            half8 b0 = *reinterpret_cast<const half8*>(BtP + sel * 4096 + brow[0] + sks[ks]);
            half8 b1 = *reinterpret_cast<const half8*>(BtP + sel * 4096 + brow[1] + sks[ks]);
            acc[0][0] = __builtin_amdgcn_mfma_f32_32x32x16_f16(a0, b0, acc[0][0], 0, 0, 0);
            acc[0][1] = __builtin_amdgcn_mfma_f32_32x32x16_f16(a0, b1, acc[0][1], 0, 0, 0);
            acc[1][0] = __builtin_amdgcn_mfma_f32_32x32x16_f16(a1, b0, acc[1][0], 0, 0, 0);
            acc[1][1] = __builtin_amdgcn_mfma_f32_32x32x16_f16(a1, b1, acc[1][1], 0, 0, 0);
        }
    };

    stage(0, 0);
    for (int i = 0; i < DIM / 32 - 1; i++) {
        const int sel = i & 1;
        SFENCE; SBAR; SFENCE;                 // WAR: compute(i-1) reads done
        stage((i + 1) * 32, sel ^ 1);
        SFENCE; VMCNT4; SFENCE;               // stage(i) landed (per wave)
        SBAR; SFENCE;                         // ... for ALL waves
        compute(sel);
    }
    SFENCE; VMCNT0; SFENCE;                   // last stage landed
    SBAR; SFENCE;
    compute((DIM / 32 - 1) & 1);
    __syncthreads();                          // pool reuse below (V path)

    const float* bias = (mat == 0) ? bq : ((mat == 1) ? bk : bv);
    const float scale = (mat == 0) ? 0.1803368801111601f : 1.0f;  // 0.125*log2(e)
    const int rowBase = rowblk * 128 + mhalf * 64;
    const int bb = rowBase / SEQ;
    const int sBase = rowBase % SEQ;

    if (mat < 2) {
        // D[row][col]: col = nhalf*64 + nt*32 + ql (= e), row = s offset.
        unsigned short* outp = (mat == 0) ? Qb : Kb;
#pragma unroll
        for (int mt = 0; mt < 2; mt++) {
#pragma unroll
            for (int nt = 0; nt < 2; nt++) {
                const int e = nhalf * 64 + nt * 32 + ql;
                const int head = hpair * 2 + (e >> 6);
                const int n = e & 63;
                const float bvl = bias[head * DH + n];
                const size_t base = (size_t)(bb * NH + head) * SEQ * DH;
#pragma unroll
                for (int r = 0; r < 16; r++) {
                    const int s = sBase + mt * 32 + (r & 3) + 8 * (r >> 2) + 4 * hi;
                    outp[base + (size_t)s * DH + n] =
                        f2h((acc[mt][nt][r] + bvl) * scale);
                }
            }
        }
    } else {
        // V: lane holds col el fixed, 16 s-values -> write 8B groups (4
        // consecutive s) into XOR-swizzled pool, then coalesced uint4 out.
#pragma unroll
        for (int mt = 0; mt < 2; mt++) {
#pragma unroll
            for (int nt = 0; nt < 2; nt++) {
                const int el = nhalf * 64 + nt * 32 + ql;  // e-local 0..127
                const int head = hpair * 2 + (el >> 6);
                const int n = el & 63;
                const float bvl = bias[head * DH + n];
                const int xsw = (el & 7) << 2;
#pragma unroll
                for (int g = 0; g < 4; g++) {
                    // s-local = mhalf*64 + mt*32 + 8g + 4hi + (0..3)
                    const int slot = mhalf * 16 + mt * 8 + 2 * g + hi;
                    uint2 w;
                    w.x = pk2u(acc[mt][nt][4 * g + 0] + bvl, acc[mt][nt][4 * g + 1] + bvl);
                    w.y = pk2u(acc[mt][nt][4 * g + 2] + bvl, acc[mt][nt][4 * g + 3] + bvl);
                    *reinterpret_cast<uint2*>(pool + el * 128 + (slot ^ xsw) * 4) = w;
                }
            }
        }
        __syncthreads();
        // Read: 16B = slots (2sc, 2sc+1)^xsw -> s = sc*8..sc*8+7 in order.
        const int blkRow = rowblk * 128;       // global s of s-local 0
        const int vb = blkRow / SEQ;           // batch of this block
        const int s0b = blkRow % SEQ;
        const int sc = threadIdx.x & 15;
        const int esub = threadIdx.x >> 4;     // 0..15
#pragma unroll
        for (int p = 0; p < 8; p++) {
            const int el = p * 16 + esub;
            const int head = hpair * 2 + (el >> 6);
            const int n = el & 63;
            const int rs = (sc * 2) ^ ((el & 7) << 2);
            uint4 v = *reinterpret_cast<const uint4*>(pool + el * 128 + rs * 4);
            const size_t base = (size_t)(vb * NH + head) * DH * SEQ;
            *reinterpret_cast<uint4*>(&Vt[base + (size_t)n * SEQ + s0b + sc * 8]) = v;
        }
    }
}

// ---------------- flash attention (32x32x16, kb-serial + counted vmcnt) -----
// 1D grid 1024, XCD-swizzled. Block 256 = 4 waves, each wave owns 32 q rows.
// Swapped QK^T, in-register softmax (v_exp_f32, cvt_pkrtz, permlane32_swap),
// kb-serial per tile (R12's proven register diet, VGPR 52). This rev adds
// the counted-vmcnt barrier scheme (4 staged loads/wave/iter -> vmcnt(4)).
__global__ __launch_bounds__(256, 4) void attn_kernel(
    const unsigned short* __restrict__ Qb,   // [B][H][S][DH] scaled by 0.125*log2e
    const unsigned short* __restrict__ Kb,   // [B][H][S][DH]
    const unsigned short* __restrict__ Vt,   // [B][H][DH][S]
    unsigned short* __restrict__ Ob)         // [B*S][DIM] f16
{
    // ---- XCD-aware decomposition ----
    const int bid = blockIdx.x;
    const int xcd = bid & 7;
    const int local = bid >> 3;            // 0..127
    const int bhg = xcd * 8 + (local >> 4);// 0..63
    const int qblk = local & 15;
    const int h = bhg & 15;
    const int bb = bhg >> 4;

    const int wave = threadIdx.x >> 6;
    const int lane = threadIdx.x & 63;
    const int ql = lane & 31;     // q column within wave tile
    const int hi = lane >> 5;     // half select
    const int qBase = qblk * 128 + wave * 32;
    const int NT = SEQ / 64;      // 32 key tiles

    const size_t bh = (size_t)(bb * NH + h);
    const unsigned short* Qh = Qb + bh * SEQ * DH;
    const unsigned short* Kh = Kb + bh * SEQ * DH;
    const unsigned short* Vh = Vt + bh * DH * SEQ;

    __shared__ __align__(16) unsigned short Kbuf[2][64 * 64];  // [key][dh] swizzled
    __shared__ __align__(16) unsigned short Vbuf[2][64 * 64];  // [dh][s]  swizzled

    // per-lane staging source offsets (loop-invariant)
    const int srow = lane >> 3;   // 0..7
    const int scs = lane & 7;     // chunk slot 0..7 (8 f16 each)
    int koff[2], voff[2];
#pragma unroll
    for (int jj = 0; jj < 2; jj++) {
        const int r = wave * 16 + jj * 8 + srow;        // 0..63
        const int cg = scs ^ srow ^ ((wave * 2 + jj) & 3);  // chunk c at slot c^(r&7)^((r>>3)&3)
        koff[jj] = r * DH + cg * 8;
        voff[jj] = r * SEQ + cg * 8;
    }

    // kt = 64-key tile index; K advances kt*64 keys, V advances kt*64 columns
    auto stage_kv = [&](int kt, int sel) {
        const size_t kb0 = (size_t)kt * 64 * DH;
        const size_t vb0 = (size_t)kt * 64;
        gl_lds16(Kh + kb0 + koff[0], &Kbuf[sel][wave * 1024]);
        gl_lds16(Kh + kb0 + koff[1], &Kbuf[sel][wave * 1024 + 512]);
        gl_lds16(Vh + vb0 + voff[0], &Vbuf[sel][wave * 1024]);
        gl_lds16(Vh + vb0 + voff[1], &Vbuf[sel][wave * 1024 + 512]);
    };

    // Q fragments (B-operand of QK^T), loop-invariant
    half8 qf[4];
#pragma unroll
    for (int ks = 0; ks < 4; ks++)
        qf[ks] = *reinterpret_cast<const half8*>(
            Qh + (size_t)(qBase + ql) * DH + ks * 16 + hi * 8);

    // precomputed LDS read offsets: row base + swizzled slot (loop-invariant)
    const int slotx = (ql & 7) ^ ((ql >> 3) & 3);
    int rowb[2], soff[4];
#pragma unroll
    for (int b = 0; b < 2; b++) rowb[b] = (b * 32 + ql) * 64;
#pragma unroll
    for (int ks = 0; ks < 4; ks++) soff[ks] = ((ks * 2 + hi) ^ slotx) * 8;

    f32x16 z16;
#pragma unroll
    for (int e = 0; e < 16; e++) z16[e] = 0.f;

    f32x16 o[2];            // O^T acc: [dh-tile of 32][16 regs]
#pragma unroll
    for (int mt = 0; mt < 2; mt++) o[mt] = z16;
    float lsA = 0.f, lsB = 0.f;

    // kb-serial tile compute: QK(kb) -> softmax(kb) -> PV(kb), kb = 0,1.
    // sacc reg r holds key (r&3)+8*(r>>2)+4*hi (+32*kb) for q=ql.
    auto compute = [&](int sel) {
#pragma unroll
        for (int kb = 0; kb < 2; kb++) {
            f32x16 sacc;
            __builtin_amdgcn_s_setprio(1);
#pragma unroll
            for (int ks = 0; ks < 4; ks++) {
                half8 kf = *reinterpret_cast<const half8*>(
                    &Kbuf[sel][rowb[kb] + soff[ks]]);
                sacc = __builtin_amdgcn_mfma_f32_32x32x16_f16(
                    kf, qf[ks], ks ? sacc : z16, 0, 0, 0);
            }
            __builtin_amdgcn_s_setprio(0);

            unsigned int c[8];
#pragma unroll
            for (int m = 0; m < 8; m++) {
                float a = fexp2(sacc[2 * m]);
                float b2 = fexp2(sacc[2 * m + 1]);
                if (m & 1) lsB += a + b2; else lsA += a + b2;
                c[m] = pk2u(a, b2);
            }

            __builtin_amdgcn_s_setprio(1);
#pragma unroll
            for (int ks = 0; ks < 2; ks++) {
                u32x2 w02 = __builtin_amdgcn_permlane32_swap(
                    c[4 * ks + 0], c[4 * ks + 2], false, false);
                u32x2 w13 = __builtin_amdgcn_permlane32_swap(
                    c[4 * ks + 1], c[4 * ks + 3], false, false);
                union { unsigned int u[4]; half8 h; } cv;
                cv.u[0] = w02[0]; cv.u[1] = w13[0];
                cv.u[2] = w02[1]; cv.u[3] = w13[1];
                const half8 pf = cv.h;
#pragma unroll
                for (int mt = 0; mt < 2; mt++) {
                    half8 vf = *reinterpret_cast<const half8*>(
                        &Vbuf[sel][rowb[mt] + soff[kb * 2 + ks]]);
                    o[mt] = __builtin_amdgcn_mfma_f32_32x32x16_f16(
                        vf, pf, o[mt], 0, 0, 0);
                }
            }
            __builtin_amdgcn_s_setprio(0);
        }
    };

    stage_kv(0, 0);
    for (int i = 0; i < NT - 1; i++) {
        const int sel = i & 1;
        SFENCE; SBAR; SFENCE;                 // WAR: compute(i-1) reads done
        stage_kv(i + 1, sel ^ 1);
        SFENCE; VMCNT4; SFENCE;               // stage(i) (+ qf) landed
        SBAR; SFENCE;                         // ... for ALL waves
        compute(sel);
    }
    SFENCE; VMCNT0; SFENCE;
    SBAR; SFENCE;
    compute((NT - 1) & 1);

    // ---- l reduce across halves, normalize, store O^T ----
    float l = lsA + lsB;
    l += __shfl_xor(l, 32);
    const float inv = 1.f / l;
    const size_t orow = (size_t)(bb * SEQ + qBase + ql) * DIM + h * DH;
#pragma unroll
    for (int mt = 0; mt < 2; mt++) {
#pragma unroll
        for (int g = 0; g < 4; g++) {
            uint2 pkd;
            pkd.x = pk2u(o[mt][4 * g + 0] * inv, o[mt][4 * g + 1] * inv);
            pkd.y = pk2u(o[mt][4 * g + 2] * inv, o[mt][4 * g + 3] * inv);
            // regs 4g..4g+3 -> dh = mt*32 + 8*g + 4*hi + (0..3)
            *reinterpret_cast<uint2*>(Ob + orow + mt * 32 + 8 * g + 4 * hi) = pkd;
        }
    }
}

// ---------------- output projection (32x32x16 MFMA, 128x128, BK=32) -------
// 1D grid 512, XCD-swizzled (bijective: 512 = 8*64). Counted-vmcnt scheme.
__global__ __launch_bounds__(256) void out_proj_kernel(
    const unsigned short* __restrict__ Ob,   // [8192][1024] f16
    const unsigned short* __restrict__ wot,  // [1024 out][1024 in] f16
    const float* __restrict__ bo,
    float* __restrict__ out)                 // [8192][1024] fp32
{
    const int bid = blockIdx.x;
    const int xcd = bid & 7;
    const int local = bid >> 3;              // 0..63
    const int rowblk = xcd * 8 + (local >> 3);
    const int colblk = local & 7;

    const int wave = threadIdx.x >> 6;
    const int lane = threadIdx.x & 63;
    const int ql = lane & 31;
    const int hi = lane >> 5;
    const int mhalf = wave & 1;
    const int nhalf = wave >> 1;

    __shared__ __align__(16) unsigned short Ab[2][128 * 32];
    __shared__ __align__(16) unsigned short Bt[2][128 * 32];

    const unsigned short* Asrc = Ob + (size_t)rowblk * 128 * DIM;
    const unsigned short* Bsrc = wot + (size_t)colblk * 128 * DIM;

    const int srow = lane >> 2;
    const int scs = lane & 3;

    f32x16 z16;
#pragma unroll
    for (int e = 0; e < 16; e++) z16[e] = 0.f;
    f32x16 acc[2][2];
#pragma unroll
    for (int mt = 0; mt < 2; mt++)
#pragma unroll
        for (int nt = 0; nt < 2; nt++) acc[mt][nt] = z16;

    auto stage = [&](int k0, int sel) {
#pragma unroll
        for (int jj = 0; jj < 2; jj++) {
            const int j = wave * 2 + jj;
            const int r = j * 16 + srow;
            const int cg = scs ^ ((srow >> 1) & 3) ^ ((j * 2 + (srow >> 3)) & 3);
            gl_lds16(Asrc + (size_t)r * DIM + k0 + cg * 8, &Ab[sel][j * 512]);
            gl_lds16(Bsrc + (size_t)r * DIM + k0 + cg * 8, &Bt[sel][j * 512]);
        }
    };

    const int slotx = ((ql >> 1) & 3) ^ ((ql >> 3) & 3);
    int arow[2], brow[2], sks[2];
#pragma unroll
    for (int t = 0; t < 2; t++) {
        arow[t] = (mhalf * 64 + t * 32 + ql) * 32;
        brow[t] = (nhalf * 64 + t * 32 + ql) * 32;
    }
#pragma unroll
    for (int ks = 0; ks < 2; ks++) sks[ks] = ((ks * 2 + hi) ^ slotx) * 8;

    auto compute = [&](int sel) {
#pragma unroll
        for (int ks = 0; ks < 2; ks++) {
            half8 a0 = *reinterpret_cast<const half8*>(&Ab[sel][arow[0] + sks[ks]]);
            half8 a1 = *reinterpret_cast<const half8*>(&Ab[sel][arow[1] + sks[ks]]);
            half8 b0 = *reinterpret_cast<const half8*>(&Bt[sel][brow[0] + sks[ks]]);
            half8 b1 = *reinterpret_cast<const half8*>(&Bt[sel][brow[1] + sks[ks]]);
            acc[0][0] = __builtin_amdgcn_mfma_f32_32x32x16_f16(a0, b0, acc[0][0], 0, 0, 0);
            acc[0][1] = __builtin_amdgcn_mfma_f32_32x32x16_f16(a0, b1, acc[0][1], 0, 0, 0);
            acc[1][0] = __builtin_amdgcn_mfma_f32_32x32x16_f16(a1, b0, acc[1][0], 0, 0, 0);
            acc[1][1] = __builtin_amdgcn_mfma_f32_32x32x16_f16(a1, b1, acc[1][1], 0, 0, 0);
        }
    };

    stage(0, 0);
    for (int i = 0; i < DIM / 32 - 1; i++) {
        const int sel = i & 1;
        SFENCE; SBAR; SFENCE;
        stage((i + 1) * 32, sel ^ 1);
        SFENCE; VMCNT4; SFENCE;
        SBAR; SFENCE;
        compute(sel);
    }
    SFENCE; VMCNT0; SFENCE;
    SBAR; SFENCE;
    compute((DIM / 32 - 1) & 1);

    const int rowBase = rowblk * 128 + mhalf * 64;
    const int colBase = colblk * 128 + nhalf * 64;
#pragma unroll
    for (int mt = 0; mt < 2; mt++) {
#pragma unroll
        for (int nt = 0; nt < 2; nt++) {
            const int col = colBase + nt * 32 + ql;
            const float bias = bo[col];
#pragma unroll
            for (int r = 0; r < 16; r++) {
                const int row = rowBase + mt * 32 + (r & 3) + 8 * (r >> 2) + 4 * hi;
                out[(size_t)row * DIM + col] = acc[mt][nt][r] + bias;
            }
        }
    }
}

// ---------------- launch ----------------

extern "C" void kernel_launch(void* const* d_in, const int* in_sizes, int n_in,
                              void* d_out, int out_size, void* d_ws, size_t ws_size,
                              hipStream_t stream) {
    const float* x  = (const float*)d_in[0];
    const float* Wq = (const float*)d_in[1];
    const float* Wk = (const float*)d_in[2];
    const float* Wv = (const float*)d_in[3];
    const float* bq = (const float*)d_in[4];
    const float* bk = (const float*)d_in[5];
    const float* bv = (const float*)d_in[6];
    const float* Wo = (const float*)d_in[7];
    const float* bo = (const float*)d_in[8];
    float* out = (float*)d_out;

    unsigned short* xh  = (unsigned short*)d_ws;                 // 8192*1024
    unsigned short* wt  = xh  + (size_t)MROWS * DIM;             // 3*16*64*1024
    unsigned short* wot = wt  + (size_t)3 * NH * DH * DIM;       // 1024*1024
    unsigned short* Qb  = wot + (size_t)DIM * DIM;               // 4*16*2048*64
    unsigned short* Kb  = Qb  + (size_t)BATCH * NH * SEQ * DH;
    unsigned short* Vt  = Kb  + (size_t)BATCH * NH * SEQ * DH;   // [B][H][DH][S]
    unsigned short* Ob  = Vt  + (size_t)BATCH * NH * SEQ * DH;

    cast_prep_kernel<<<9216, 256, 0, stream>>>(x, xh, Wq, Wk, Wv, Wo, wt, wot);
    qkv_gemm_kernel<<<1536, 256, 0, stream>>>(xh, wt, bq, bk, bv, Qb, Kb, Vt);
    attn_kernel<<<1024, 256, 0, stream>>>(Qb, Kb, Vt, Ob);
    out_proj_kernel<<<512, 256, 0, stream>>>(Ob, wot, bo, out);
}

// Round 14
// 279.121 us; speedup vs baseline: 1.0770x; 1.0770x over previous
//
#include <hip/hip_runtime.h>
#include <stdint.h>

#define DIM 1024
#define NH 16
#define DH 64
#define BATCH 4
#define SEQ 2048
#define MROWS (BATCH*SEQ)  // 8192

typedef _Float16 half8 __attribute__((ext_vector_type(8)));
typedef __fp16 fp16x2 __attribute__((ext_vector_type(2)));
typedef float f32x4 __attribute__((ext_vector_type(4)));
typedef float f32x16 __attribute__((ext_vector_type(16)));
typedef unsigned int u32x2 __attribute__((ext_vector_type(2)));

__device__ __forceinline__ unsigned short f2h(float f) {
    union { _Float16 h; unsigned short u; } c; c.h = (_Float16)f; return c.u;
}
__device__ __forceinline__ unsigned int pk2u(float a, float b) {
    union { fp16x2 h; unsigned int u; } c;
    c.h = __builtin_amdgcn_cvt_pkrtz(a, b);
    return c.u;
}
// raw v_exp_f32 (1 inst; exp2f without -ffast-math goes through ocml libm)
__device__ __forceinline__ float fexp2(float x) {
    return __builtin_amdgcn_exp2f(x);
}
// async 16B/lane global->LDS (lds dest = wave-uniform base + lane*16)
__device__ __forceinline__ void gl_lds16(const unsigned short* g, unsigned short* l) {
    __builtin_amdgcn_global_load_lds(
        (__attribute__((address_space(1))) void*)(void*)g,
        (__attribute__((address_space(3))) void*)(void*)l,
        16, 0, 0);
}

// ---------------- merged cast + weight prep (one launch) ----------------
// 1D grid 9216: blocks 0..8191 cast x (fp32->f16, 1024 float4/block exact);
// blocks 8192..9215 decode (d0, y, mat): mat 0..2 -> wt transpose, 3 -> wot.
__global__ __launch_bounds__(256) void cast_prep_kernel(
    const float* __restrict__ x, unsigned short* __restrict__ xh,
    const float* __restrict__ Wq, const float* __restrict__ Wk,
    const float* __restrict__ Wv, const float* __restrict__ Wo,
    unsigned short* __restrict__ wt, unsigned short* __restrict__ wot)
{
    __shared__ unsigned short tile[64][65];
    const int bid = blockIdx.x;
    if (bid < 8192) {
        const int i = bid * 256 + threadIdx.x;   // n4 = 8192*256 exactly
        float4 v = reinterpret_cast<const float4*>(x)[i];
        uint2 o;
        o.x = pk2u(v.x, v.y);
        o.y = pk2u(v.z, v.w);
        reinterpret_cast<uint2*>(xh)[i] = o;
        return;
    }
    const int local = bid - 8192;
    const int d0 = (local & 15) * 64;
    const int y = (local >> 4) & 15;
    const int mat = local >> 8;
    const int c = threadIdx.x & 63;
    const int rr = threadIdx.x >> 6;

    if (mat < 3) {
        const float* W = (mat == 0) ? Wq : ((mat == 1) ? Wk : Wv);
#pragma unroll
        for (int p = 0; p < 16; p++) {
            int dl = p * 4 + rr;
            tile[dl][c] = f2h(W[((size_t)y * 1024 + d0 + dl) * 64 + c]);
        }
        __syncthreads();
#pragma unroll
        for (int p = 0; p < 16; p++) {
            int el = p * 4 + rr;
            wt[(((size_t)(mat * NH + y) * 64) + el) * DIM + d0 + c] = tile[c][el];
        }
    } else {
        const int o0 = y * 64;
#pragma unroll
        for (int p = 0; p < 16; p++) {
            int dl = p * 4 + rr;
            tile[dl][c] = f2h(Wo[(size_t)(d0 + dl) * DIM + o0 + c]);
        }
        __syncthreads();
#pragma unroll
        for (int p = 0; p < 16; p++) {
            int ol = p * 4 + rr;
            wot[(size_t)(o0 + ol) * DIM + d0 + c] = tile[c][ol];
        }
    }
}

// ---------------- QKV projection GEMM (32x32x16 MFMA, 128x128, BK=32) ----
// 1D grid 1536, XCD-swizzled (bijective: 1536 = 8*192). 8 MFMA/K-step.
// Layouts are the session-verified 32x32 mappings. mat==2 (V) transposes
// through the dead 32KB staging pool (XOR slot swizzle).
__global__ __launch_bounds__(256) void qkv_gemm_kernel(
    const unsigned short* __restrict__ xh,   // [8192][1024] f16
    const unsigned short* __restrict__ wt,   // [3][16][64][1024] f16
    const float* __restrict__ bq, const float* __restrict__ bk,
    const float* __restrict__ bv,
    unsigned short* __restrict__ Qb,         // [B][H][S][DH] (scaled)
    unsigned short* __restrict__ Kb,         // [B][H][S][DH]
    unsigned short* __restrict__ Vt)         // [B][H][DH][S]
{
    // ---- XCD-aware decomposition (bijective: 1536 = 8 * 192) ----
    const int bid = blockIdx.x;
    const int xcd = bid & 7;
    const int local = bid >> 3;              // 0..191
    const int rowblk = xcd * 8 + local / 24; // 0..63
    const int rem = local % 24;
    const int hpair = rem & 7;
    const int mat = rem >> 3;                // 0..2

    const int wave = threadIdx.x >> 6;
    const int lane = threadIdx.x & 63;
    const int ql = lane & 31;
    const int hi = lane >> 5;
    const int mhalf = wave & 1;
    const int nhalf = wave >> 1;

    // pool: staging Ab[2]/Bt[2] (32KB) OR V-transpose tile [128 e][128 s] swz
    __shared__ __align__(16) unsigned short pool[16384];
    unsigned short* AbP = pool;              // [2][128*32]
    unsigned short* BtP = pool + 8192;       // [2][128*32]

    const unsigned short* Asrc = xh + (size_t)rowblk * 128 * DIM;
    const unsigned short* Bsrc = wt + (size_t)(mat * NH + hpair * 2) * DH * DIM;

    const int srow = lane >> 2;    // 0..15 row within 16-row group
    const int scs = lane & 3;      // chunk slot 0..3 (8 f16 each)

    f32x16 z16;
#pragma unroll
    for (int e = 0; e < 16; e++) z16[e] = 0.f;
    f32x16 acc[2][2];
#pragma unroll
    for (int mt = 0; mt < 2; mt++)
#pragma unroll
        for (int nt = 0; nt < 2; nt++) acc[mt][nt] = z16;

    // staging: chunk c of row r lands at slot c ^ ((r>>1)&3) ^ ((r>>3)&3)
    auto stage = [&](int k0, int sel) {
#pragma unroll
        for (int jj = 0; jj < 2; jj++) {
            const int j = wave * 2 + jj;            // 0..7 (16 rows each)
            const int r = j * 16 + srow;            // 0..127
            const int cg = scs ^ ((srow >> 1) & 3) ^ ((j * 2 + (srow >> 3)) & 3);
            gl_lds16(Asrc + (size_t)r * DIM + k0 + cg * 8, AbP + sel * 4096 + j * 512);
            gl_lds16(Bsrc + (size_t)r * DIM + k0 + cg * 8, BtP + sel * 4096 + j * 512);
        }
    };

    // read offsets (loop-invariant): row = base + ql -> swz depends on ql only
    const int slotx = ((ql >> 1) & 3) ^ ((ql >> 3) & 3);
    int arow[2], brow[2], sks[2];
#pragma unroll
    for (int t = 0; t < 2; t++) {
        arow[t] = (mhalf * 64 + t * 32 + ql) * 32;
        brow[t] = (nhalf * 64 + t * 32 + ql) * 32;
    }
#pragma unroll
    for (int ks = 0; ks < 2; ks++) sks[ks] = ((ks * 2 + hi) ^ slotx) * 8;

    stage(0, 0);
    __syncthreads();

    for (int i = 0; i < DIM / 32; i++) {
        const int sel = i & 1;
        if (i + 1 < DIM / 32) stage((i + 1) * 32, sel ^ 1);

#pragma unroll
        for (int ks = 0; ks < 2; ks++) {
            half8 a0 = *reinterpret_cast<const half8*>(AbP + sel * 4096 + arow[0] + sks[ks]);
            half8 a1 = *reinterpret_cast<const half8*>(AbP + sel * 4096 + arow[1] + sks[ks]);
            half8 b0 = *reinterpret_cast<const half8*>(BtP + sel * 4096 + brow[0] + sks[ks]);
            half8 b1 = *reinterpret_cast<const half8*>(BtP + sel * 4096 + brow[1] + sks[ks]);
            acc[0][0] = __builtin_amdgcn_mfma_f32_32x32x16_f16(a0, b0, acc[0][0], 0, 0, 0);
            acc[0][1] = __builtin_amdgcn_mfma_f32_32x32x16_f16(a0, b1, acc[0][1], 0, 0, 0);
            acc[1][0] = __builtin_amdgcn_mfma_f32_32x32x16_f16(a1, b0, acc[1][0], 0, 0, 0);
            acc[1][1] = __builtin_amdgcn_mfma_f32_32x32x16_f16(a1, b1, acc[1][1], 0, 0, 0);
        }
        __syncthreads();
    }

    const float* bias = (mat == 0) ? bq : ((mat == 1) ? bk : bv);
    const float scale = (mat == 0) ? 0.1803368801111601f : 1.0f;  // 0.125*log2(e)
    const int rowBase = rowblk * 128 + mhalf * 64;
    const int bb = rowBase / SEQ;
    const int sBase = rowBase % SEQ;

    if (mat < 2) {
        // D[row][col]: col = nhalf*64 + nt*32 + ql (= e), row = s offset.
        unsigned short* outp = (mat == 0) ? Qb : Kb;
#pragma unroll
        for (int mt = 0; mt < 2; mt++) {
#pragma unroll
            for (int nt = 0; nt < 2; nt++) {
                const int e = nhalf * 64 + nt * 32 + ql;
                const int head = hpair * 2 + (e >> 6);
                const int n = e & 63;
                const float bvl = bias[head * DH + n];
                const size_t base = (size_t)(bb * NH + head) * SEQ * DH;
#pragma unroll
                for (int r = 0; r < 16; r++) {
                    const int s = sBase + mt * 32 + (r & 3) + 8 * (r >> 2) + 4 * hi;
                    outp[base + (size_t)s * DH + n] =
                        f2h((acc[mt][nt][r] + bvl) * scale);
                }
            }
        }
    } else {
        // V: lane holds col el fixed, 16 s-values -> write 8B groups (4
        // consecutive s) into XOR-swizzled pool, then coalesced uint4 out.
#pragma unroll
        for (int mt = 0; mt < 2; mt++) {
#pragma unroll
            for (int nt = 0; nt < 2; nt++) {
                const int el = nhalf * 64 + nt * 32 + ql;  // e-local 0..127
                const int head = hpair * 2 + (el >> 6);
                const int n = el & 63;
                const float bvl = bias[head * DH + n];
                const int xsw = (el & 7) << 2;
#pragma unroll
                for (int g = 0; g < 4; g++) {
                    // s-local = mhalf*64 + mt*32 + 8g + 4hi + (0..3)
                    const int slot = mhalf * 16 + mt * 8 + 2 * g + hi;
                    uint2 w;
                    w.x = pk2u(acc[mt][nt][4 * g + 0] + bvl, acc[mt][nt][4 * g + 1] + bvl);
                    w.y = pk2u(acc[mt][nt][4 * g + 2] + bvl, acc[mt][nt][4 * g + 3] + bvl);
                    *reinterpret_cast<uint2*>(pool + el * 128 + (slot ^ xsw) * 4) = w;
                }
            }
        }
        __syncthreads();
        // Read: 16B = slots (2sc, 2sc+1)^xsw -> s = sc*8..sc*8+7 in order.
        const int blkRow = rowblk * 128;       // global s of s-local 0
        const int vb = blkRow / SEQ;           // batch of this block
        const int s0b = blkRow % SEQ;
        const int sc = threadIdx.x & 15;
        const int esub = threadIdx.x >> 4;     // 0..15
#pragma unroll
        for (int p = 0; p < 8; p++) {
            const int el = p * 16 + esub;
            const int head = hpair * 2 + (el >> 6);
            const int n = el & 63;
            const int rs = (sc * 2) ^ ((el & 7) << 2);
            uint4 v = *reinterpret_cast<const uint4*>(pool + el * 128 + rs * 4);
            const size_t base = (size_t)(vb * NH + head) * DH * SEQ;
            *reinterpret_cast<uint4*>(&Vt[base + (size_t)n * SEQ + s0b + sc * 8]) = v;
        }
    }
}

// ---------------- flash attention (32x32x16, kb-serial register diet) -----
// 1D grid 1024, XCD-swizzled. Block 256 = 4 waves, each wave owns 32 q rows.
// Swapped QK^T, in-register softmax (v_exp_f32, cvt_pkrtz, permlane32_swap).
// kb-serial per tile: QK(kb) -> softmax(kb) -> PV(kb) -- sacc is 16 regs,
// pf transient -> VGPR 52, attn 86us (session best). stage(i+1) issued
// before compute(i) so staged loads fly under the compute phase.
__global__ __launch_bounds__(256, 4) void attn_kernel(
    const unsigned short* __restrict__ Qb,   // [B][H][S][DH] scaled by 0.125*log2e
    const unsigned short* __restrict__ Kb,   // [B][H][S][DH]
    const unsigned short* __restrict__ Vt,   // [B][H][DH][S]
    unsigned short* __restrict__ Ob)         // [B*S][DIM] f16
{
    // ---- XCD-aware decomposition ----
    const int bid = blockIdx.x;
    const int xcd = bid & 7;
    const int local = bid >> 3;            // 0..127
    const int bhg = xcd * 8 + (local >> 4);// 0..63
    const int qblk = local & 15;
    const int h = bhg & 15;
    const int bb = bhg >> 4;

    const int wave = threadIdx.x >> 6;
    const int lane = threadIdx.x & 63;
    const int ql = lane & 31;     // q column within wave tile
    const int hi = lane >> 5;     // half select
    const int qBase = qblk * 128 + wave * 32;

    const size_t bh = (size_t)(bb * NH + h);
    const unsigned short* Qh = Qb + bh * SEQ * DH;
    const unsigned short* Kh = Kb + bh * SEQ * DH;
    const unsigned short* Vh = Vt + bh * DH * SEQ;

    __shared__ __align__(16) unsigned short Kbuf[2][64 * 64];  // [key][dh] swizzled
    __shared__ __align__(16) unsigned short Vbuf[2][64 * 64];  // [dh][s]  swizzled

    // per-lane staging source offsets (loop-invariant)
    const int srow = lane >> 3;   // 0..7
    const int scs = lane & 7;     // chunk slot 0..7 (8 f16 each)
    int koff[2], voff[2];
#pragma unroll
    for (int jj = 0; jj < 2; jj++) {
        const int r = wave * 16 + jj * 8 + srow;        // 0..63
        const int cg = scs ^ srow ^ ((wave * 2 + jj) & 3);  // chunk c at slot c^(r&7)^((r>>3)&3)
        koff[jj] = r * DH + cg * 8;
        voff[jj] = r * SEQ + cg * 8;
    }

    // kt = 64-key tile index; K advances kt*64 keys, V advances kt*64 columns
    auto stage_k = [&](int kt, int sel) {
        const size_t base = (size_t)kt * 64 * DH;
        gl_lds16(Kh + base + koff[0], &Kbuf[sel][wave * 1024]);
        gl_lds16(Kh + base + koff[1], &Kbuf[sel][wave * 1024 + 512]);
    };
    auto stage_v = [&](int kt, int sel) {
        const size_t base = (size_t)kt * 64;
        gl_lds16(Vh + base + voff[0], &Vbuf[sel][wave * 1024]);
        gl_lds16(Vh + base + voff[1], &Vbuf[sel][wave * 1024 + 512]);
    };

    // Q fragments (B-operand of QK^T), loop-invariant
    half8 qf[4];
#pragma unroll
    for (int ks = 0; ks < 4; ks++)
        qf[ks] = *reinterpret_cast<const half8*>(
            Qh + (size_t)(qBase + ql) * DH + ks * 16 + hi * 8);

    // precomputed LDS read offsets: row base + swizzled slot (loop-invariant)
    const int slotx = (ql & 7) ^ ((ql >> 3) & 3);
    int rowb[2], soff[4];
#pragma unroll
    for (int b = 0; b < 2; b++) rowb[b] = (b * 32 + ql) * 64;
#pragma unroll
    for (int ks = 0; ks < 4; ks++) soff[ks] = ((ks * 2 + hi) ^ slotx) * 8;

    f32x16 z16;
#pragma unroll
    for (int e = 0; e < 16; e++) z16[e] = 0.f;

    f32x16 o[2];            // O^T acc: [dh-tile of 32][16 regs]
#pragma unroll
    for (int mt = 0; mt < 2; mt++) o[mt] = z16;
    float lsA = 0.f, lsB = 0.f;

    // kb-serial tile compute: QK(kb) -> softmax(kb) -> PV(kb), kb = 0,1.
    // sacc reg r holds key (r&3)+8*(r>>2)+4*hi (+32*kb) for q=ql.
    auto compute = [&](int sel) {
#pragma unroll
        for (int kb = 0; kb < 2; kb++) {
            f32x16 sacc;
            __builtin_amdgcn_s_setprio(1);
#pragma unroll
            for (int ks = 0; ks < 4; ks++) {
                half8 kf = *reinterpret_cast<const half8*>(
                    &Kbuf[sel][rowb[kb] + soff[ks]]);
                sacc = __builtin_amdgcn_mfma_f32_32x32x16_f16(
                    kf, qf[ks], ks ? sacc : z16, 0, 0, 0);
            }
            __builtin_amdgcn_s_setprio(0);

            unsigned int c[8];
#pragma unroll
            for (int m = 0; m < 8; m++) {
                float a = fexp2(sacc[2 * m]);
                float b2 = fexp2(sacc[2 * m + 1]);
                if (m & 1) lsB += a + b2; else lsA += a + b2;
                c[m] = pk2u(a, b2);
            }

            __builtin_amdgcn_s_setprio(1);
#pragma unroll
            for (int ks = 0; ks < 2; ks++) {
                u32x2 w02 = __builtin_amdgcn_permlane32_swap(
                    c[4 * ks + 0], c[4 * ks + 2], false, false);
                u32x2 w13 = __builtin_amdgcn_permlane32_swap(
                    c[4 * ks + 1], c[4 * ks + 3], false, false);
                union { unsigned int u[4]; half8 h; } cv;
                cv.u[0] = w02[0]; cv.u[1] = w13[0];
                cv.u[2] = w02[1]; cv.u[3] = w13[1];
                const half8 pf = cv.h;
#pragma unroll
                for (int mt = 0; mt < 2; mt++) {
                    half8 vf = *reinterpret_cast<const half8*>(
                        &Vbuf[sel][rowb[mt] + soff[kb * 2 + ks]]);
                    o[mt] = __builtin_amdgcn_mfma_f32_32x32x16_f16(
                        vf, pf, o[mt], 0, 0, 0);
                }
            }
            __builtin_amdgcn_s_setprio(0);
        }
    };

    stage_k(0, 0);
    stage_v(0, 0);
    __syncthreads();

    for (int i = 0; i < SEQ / 64; i++) {
        const int sel = i & 1;
        if (i + 1 < SEQ / 64) {
            stage_k(i + 1, sel ^ 1);
            stage_v(i + 1, sel ^ 1);
        }
        compute(sel);
        __syncthreads();
    }

    // ---- l reduce across halves, normalize, store O^T ----
    float l = lsA + lsB;
    l += __shfl_xor(l, 32);
    const float inv = 1.f / l;
    const size_t orow = (size_t)(bb * SEQ + qBase + ql) * DIM + h * DH;
#pragma unroll
    for (int mt = 0; mt < 2; mt++) {
#pragma unroll
        for (int g = 0; g < 4; g++) {
            uint2 pkd;
            pkd.x = pk2u(o[mt][4 * g + 0] * inv, o[mt][4 * g + 1] * inv);
            pkd.y = pk2u(o[mt][4 * g + 2] * inv, o[mt][4 * g + 3] * inv);
            // regs 4g..4g+3 -> dh = mt*32 + 8*g + 4*hi + (0..3)
            *reinterpret_cast<uint2*>(Ob + orow + mt * 32 + 8 * g + 4 * hi) = pkd;
        }
    }
}

// ---------------- output projection (32x32x16 MFMA, 128x128, BK=32) -------
// 1D grid 512, XCD-swizzled (bijective: 512 = 8*64).
__global__ __launch_bounds__(256) void out_proj_kernel(
    const unsigned short* __restrict__ Ob,   // [8192][1024] f16
    const unsigned short* __restrict__ wot,  // [1024 out][1024 in] f16
    const float* __restrict__ bo,
    float* __restrict__ out)                 // [8192][1024] fp32
{
    const int bid = blockIdx.x;
    const int xcd = bid & 7;
    const int local = bid >> 3;              // 0..63
    const int rowblk = xcd * 8 + (local >> 3);
    const int colblk = local & 7;

    const int wave = threadIdx.x >> 6;
    const int lane = threadIdx.x & 63;
    const int ql = lane & 31;
    const int hi = lane >> 5;
    const int mhalf = wave & 1;
    const int nhalf = wave >> 1;

    __shared__ __align__(16) unsigned short Ab[2][128 * 32];
    __shared__ __align__(16) unsigned short Bt[2][128 * 32];

    const unsigned short* Asrc = Ob + (size_t)rowblk * 128 * DIM;
    const unsigned short* Bsrc = wot + (size_t)colblk * 128 * DIM;

    const int srow = lane >> 2;
    const int scs = lane & 3;

    f32x16 z16;
#pragma unroll
    for (int e = 0; e < 16; e++) z16[e] = 0.f;
    f32x16 acc[2][2];
#pragma unroll
    for (int mt = 0; mt < 2; mt++)
#pragma unroll
        for (int nt = 0; nt < 2; nt++) acc[mt][nt] = z16;

    auto stage = [&](int k0, int sel) {
#pragma unroll
        for (int jj = 0; jj < 2; jj++) {
            const int j = wave * 2 + jj;
            const int r = j * 16 + srow;
            const int cg = scs ^ ((srow >> 1) & 3) ^ ((j * 2 + (srow >> 3)) & 3);
            gl_lds16(Asrc + (size_t)r * DIM + k0 + cg * 8, &Ab[sel][j * 512]);
            gl_lds16(Bsrc + (size_t)r * DIM + k0 + cg * 8, &Bt[sel][j * 512]);
        }
    };

    const int slotx = ((ql >> 1) & 3) ^ ((ql >> 3) & 3);
    int arow[2], brow[2], sks[2];
#pragma unroll
    for (int t = 0; t < 2; t++) {
        arow[t] = (mhalf * 64 + t * 32 + ql) * 32;
        brow[t] = (nhalf * 64 + t * 32 + ql) * 32;
    }
#pragma unroll
    for (int ks = 0; ks < 2; ks++) sks[ks] = ((ks * 2 + hi) ^ slotx) * 8;

    stage(0, 0);
    __syncthreads();

    for (int i = 0; i < DIM / 32; i++) {
        const int sel = i & 1;
        if (i + 1 < DIM / 32) stage((i + 1) * 32, sel ^ 1);

#pragma unroll
        for (int ks = 0; ks < 2; ks++) {
            half8 a0 = *reinterpret_cast<const half8*>(&Ab[sel][arow[0] + sks[ks]]);
            half8 a1 = *reinterpret_cast<const half8*>(&Ab[sel][arow[1] + sks[ks]]);
            half8 b0 = *reinterpret_cast<const half8*>(&Bt[sel][brow[0] + sks[ks]]);
            half8 b1 = *reinterpret_cast<const half8*>(&Bt[sel][brow[1] + sks[ks]]);
            acc[0][0] = __builtin_amdgcn_mfma_f32_32x32x16_f16(a0, b0, acc[0][0], 0, 0, 0);
            acc[0][1] = __builtin_amdgcn_mfma_f32_32x32x16_f16(a0, b1, acc[0][1], 0, 0, 0);
            acc[1][0] = __builtin_amdgcn_mfma_f32_32x32x16_f16(a1, b0, acc[1][0], 0, 0, 0);
            acc[1][1] = __builtin_amdgcn_mfma_f32_32x32x16_f16(a1, b1, acc[1][1], 0, 0, 0);
        }
        __syncthreads();
    }

    const int rowBase = rowblk * 128 + mhalf * 64;
    const int colBase = colblk * 128 + nhalf * 64;
#pragma unroll
    for (int mt = 0; mt < 2; mt++) {
#pragma unroll
        for (int nt = 0; nt < 2; nt++) {
            const int col = colBase + nt * 32 + ql;
            const float bias = bo[col];
#pragma unroll
            for (int r = 0; r < 16; r++) {
                const int row = rowBase + mt * 32 + (r & 3) + 8 * (r >> 2) + 4 * hi;
                out[(size_t)row * DIM + col] = acc[mt][nt][r] + bias;
            }
        }
    }
}

// ---------------- launch ----------------

extern "C" void kernel_launch(void* const* d_in, const int* in_sizes, int n_in,
                              void* d_out, int out_size, void* d_ws, size_t ws_size,
                              hipStream_t stream) {
    const float* x  = (const float*)d_in[0];
    const float* Wq = (const float*)d_in[1];
    const float* Wk = (const float*)d_in[2];
    const float* Wv = (const float*)d_in[3];
    const float* bq = (const float*)d_in[4];
    const float* bk = (const float*)d_in[5];
    const float* bv = (const float*)d_in[6];
    const float* Wo = (const float*)d_in[7];
    const float* bo = (const float*)d_in[8];
    float* out = (float*)d_out;

    unsigned short* xh  = (unsigned short*)d_ws;                 // 8192*1024
    unsigned short* wt  = xh  + (size_t)MROWS * DIM;             // 3*16*64*1024
    unsigned short* wot = wt  + (size_t)3 * NH * DH * DIM;       // 1024*1024
    unsigned short* Qb  = wot + (size_t)DIM * DIM;               // 4*16*2048*64
    unsigned short* Kb  = Qb  + (size_t)BATCH * NH * SEQ * DH;
    unsigned short* Vt  = Kb  + (size_t)BATCH * NH * SEQ * DH;   // [B][H][DH][S]
    unsigned short* Ob  = Vt  + (size_t)BATCH * NH * SEQ * DH;

    cast_prep_kernel<<<9216, 256, 0, stream>>>(x, xh, Wq, Wk, Wv, Wo, wt, wot);
    qkv_gemm_kernel<<<1536, 256, 0, stream>>>(xh, wt, bq, bk, bv, Qb, Kb, Vt);
    attn_kernel<<<1024, 256, 0, stream>>>(Qb, Kb, Vt, Ob);
    out_proj_kernel<<<512, 256, 0, stream>>>(Ob, wot, bo, out);
}